// Round 6
// baseline (20.300 us; speedup 1.0000x reference)
//
#include <hip/hip_runtime.h>

#define TILE 16
#define PPT 64
#define G 4            // points per prefetch group
#define NG (PPT / G)   // 16 groups

#if __has_builtin(__builtin_amdgcn_exp2f)
#define EXP2F(x) __builtin_amdgcn_exp2f(x)
#else
#define EXP2F(x) exp2f(x)
#endif

// Robustly read a small positive integer scalar that may have been stored
// as int32 or float32 bits.
__device__ __forceinline__ int read_dim(const int* p) {
    int v = *p;
    if (v >= TILE && v <= 65536 && (v % TILE) == 0) return v;
    float f = __int_as_float(v);
    return (int)f;
}

// One compositing step for one pixel. Log2-domain: e = log2(dens*alpha).
//  - vis test on e (pre-exp, overlaps v_exp latency)
//  - w = Tg_old - Tone  (== alpha_c * Ti, telescoping; norm = 1 - T_final)
//  - Tg is the gated transmittance: set to 0 on the saturation trigger so
//    Tone==0 < 1e-4 forever after (no explicit sat flag needed);
//    T is the true output transmittance (frozen once contributions stop).
__device__ __forceinline__ void composite(
    float dy, float q, float base, float pcc,
    float cr, float cg, float cb, float cd, int jp1,
    float& T, float& Tg, float& ar, float& ag, float& ab, float& ad,
    int& cnt, int& last)
{
    const float e     = fmaf(fmaf(pcc, dy, q), dy, base);
    const bool  vis   = e >= -7.9943533f;          // log2(1/255)
    const float alpha = EXP2F(e);
    const float one_m = fmaxf(1.0f - alpha, 0.01f); // = 1 - min(alpha,0.99)
    const float Tone  = Tg * one_m;
    const bool  contrib = vis && (Tone >= 1e-4f);
    const float w = contrib ? (Tg - Tone) : 0.0f;
    ar = fmaf(w, cr, ar);  ag = fmaf(w, cg, ag);
    ab = fmaf(w, cb, ab);  ad = fmaf(w, cd, ad);
    cnt += contrib;
    last = contrib ? jp1 : last;
    T  = contrib ? Tone : T;
    Tg = vis ? (contrib ? Tone : 0.0f) : Tg;
}

// One block = one tile = 128 threads (2 waves); thread p composites pixels
// (pv, pu) and (pv+8, pu) — same column, sharing dx/q/base per point.
// LDS point data is consumed through a register ping-pong: group g+1's
// ds_reads are issued BEFORE group g's compute and BEFORE the break check,
// so load latency is never control-dependent on the saturation branch.
__global__ __launch_bounds__(128, 2) void gsplat_raster_kernel(
    const float* __restrict__ point_uv,          // (N,2)
    const float* __restrict__ point_conic,       // (N,3)
    const float* __restrict__ point_alpha,       // (N,)
    const float* __restrict__ point_color,       // (N,3)
    const float* __restrict__ point_depth,       // (N,)
    const int*   __restrict__ tile_point_indices,// (NT,PPT)
    const int*   __restrict__ cam_h_p,
    const int*   __restrict__ cam_w_p,
    float* __restrict__ out)
{
    const int t = blockIdx.x;
    const int p = threadIdx.x;   // 0..127

    const int W  = read_dim(cam_w_p);
    const int H  = read_dim(cam_h_p);
    const int TU = W / TILE;
    const int n_pix = H * W;

    // sA = {u, v, -0.5*log2e*a, -0.5*log2e*c}; sB = {-log2e*b, log2(alpha)};
    // sC = {r, g, b, depth} (f32 colors: no cvt in the hot loop)
    __shared__ float4 sA[PPT];
    __shared__ float2 sB[PPT];
    __shared__ float4 sC[PPT];

    const float L2E = 1.4426950408889634f;
    if (p < PPT) {                       // wave 0: geometry side
        const int gi = tile_point_indices[t * PPT + p];
        const float2 uv = ((const float2*)point_uv)[gi];
        sA[p] = make_float4(uv.x, uv.y,
                            -0.5f * L2E * point_conic[gi * 3 + 0],
                            -0.5f * L2E * point_conic[gi * 3 + 2]);
        sB[p] = make_float2(-L2E * point_conic[gi * 3 + 1],
                            __log2f(point_alpha[gi]));
    } else {                             // wave 1: color/depth side
        const int q  = p - PPT;
        const int gi = tile_point_indices[t * PPT + q];
        sC[q] = make_float4(point_color[gi * 3 + 0],
                            point_color[gi * 3 + 1],
                            point_color[gi * 3 + 2],
                            point_depth[gi]);
    }
    __syncthreads();

    const int tu  = t % TU;
    const int tv  = t / TU;
    const int pu  = p % TILE;      // column within tile
    const int pv0 = p / TILE;      // rows 0..7 (pixel 1 = row pv0+8)
    const float pix_u  = (float)(tu * TILE + pu) + 0.5f;
    const float pix_v0 = (float)(tv * TILE + pv0) + 0.5f;

    float T0 = 1.0f, T1 = 1.0f, Tg0 = 1.0f, Tg1 = 1.0f;
    float r0 = 0.f, g0 = 0.f, b0 = 0.f, d0 = 0.f;
    float r1 = 0.f, g1 = 0.f, b1 = 0.f, d1 = 0.f;
    int cnt0 = 0, cnt1 = 0, last0 = 0, last1 = 0;

    // register ping-pong buffers (all indices compile-time -> stay in VGPRs)
    float4 A0[G], C0[G]; float2 B0[G];
    float4 A1[G], C1[G]; float2 B1[G];

#define LOADG(BUF, g) do { const int _gb = (g) * G;                          \
    _Pragma("unroll") for (int k = 0; k < G; ++k) {                          \
        A##BUF[k] = sA[_gb + k];                                             \
        B##BUF[k] = sB[_gb + k];                                             \
        C##BUF[k] = sC[_gb + k];                                             \
    } } while (0)

#define COMPUTEG(BUF, g) do { const int _gb = (g) * G;                       \
    _Pragma("unroll") for (int k = 0; k < G; ++k) {                          \
        const float4 A = A##BUF[k];                                          \
        const float2 B = B##BUF[k];                                          \
        const float4 C = C##BUF[k];                                          \
        const float dx   = pix_u - A.x;                                      \
        const float q    = B.x * dx;                  /* pb*dx          */   \
        const float base = fmaf(A.z * dx, dx, B.y);   /* pa*dx^2 + lal  */   \
        const float dy0  = pix_v0 - A.y;                                     \
        const float dy1  = dy0 + 8.0f;                                       \
        const int   jp1  = _gb + k + 1;                                      \
        composite(dy0, q, base, A.w, C.x, C.y, C.z, C.w, jp1,                \
                  T0, Tg0, r0, g0, b0, d0, cnt0, last0);                     \
        composite(dy1, q, base, A.w, C.x, C.y, C.z, C.w, jp1,                \
                  T1, Tg1, r1, g1, b1, d1, cnt1, last1);                     \
    } } while (0)

    LOADG(0, 0);
    #pragma unroll 1
    for (int g = 0; g < NG; g += 2) {
        LOADG(1, g + 1);                 // prefetch before compute & break
        COMPUTEG(0, g);
        if (__all((Tg0 == 0.0f) && (Tg1 == 0.0f))) break;
        const int gn = (g + 2 < NG) ? g + 2 : NG - 1;   // clamped (dead if exit)
        LOADG(0, gn);
        COMPUTEG(1, g + 1);
        if (__all((Tg0 == 0.0f) && (Tg1 == 0.0f))) break;
    }

#undef LOADG
#undef COMPUTEG

    // ---- write outputs (image layout) ----
    const int c    = tu * TILE + pu;
    const int row0 = tv * TILE + pv0;
    const int pix0 = row0 * W + c;
    const int pix1 = pix0 + 8 * W;

    const float norm0 = 1.0f - T0;   // == sum(w) by telescoping
    const float norm1 = 1.0f - T1;

    out[pix0 * 3 + 0] = r0;
    out[pix0 * 3 + 1] = g0;
    out[pix0 * 3 + 2] = b0;
    out[n_pix * 3 + pix0] = d0 / fmaxf(norm0, 1e-6f);
    out[n_pix * 4 + pix0] = norm0;
    out[n_pix * 5 + pix0] = (float)(t * PPT + last0);
    out[n_pix * 6 + pix0] = (float)cnt0;

    out[pix1 * 3 + 0] = r1;
    out[pix1 * 3 + 1] = g1;
    out[pix1 * 3 + 2] = b1;
    out[n_pix * 3 + pix1] = d1 / fmaxf(norm1, 1e-6f);
    out[n_pix * 4 + pix1] = norm1;
    out[n_pix * 5 + pix1] = (float)(t * PPT + last1);
    out[n_pix * 6 + pix1] = (float)cnt1;
}

extern "C" void kernel_launch(void* const* d_in, const int* in_sizes, int n_in,
                              void* d_out, int out_size, void* d_ws, size_t ws_size,
                              hipStream_t stream) {
    const float* point_uv    = (const float*)d_in[0];
    const float* point_conic = (const float*)d_in[1];
    const float* point_alpha = (const float*)d_in[2];
    const float* point_color = (const float*)d_in[3];
    const float* point_depth = (const float*)d_in[4];
    const int*   tpi         = (const int*)d_in[5];
    const int*   cam_h       = (const int*)d_in[6];
    const int*   cam_w       = (const int*)d_in[7];

    const int NT = in_sizes[5] / PPT;  // number of tiles

    gsplat_raster_kernel<<<NT, 128, 0, stream>>>(
        point_uv, point_conic, point_alpha, point_color, point_depth,
        tpi, cam_h, cam_w, (float*)d_out);
}